// Round 9
// baseline (7091.434 us; speedup 1.0000x reference)
//
// R9: persistent scan returns, with an LLC-native barrier (R7 post-mortem:
// ACQUIRE-per-poll = L2 invalidate per poll; threadfence = L2 writeback/step).
// All cross-block h traffic now uses RELAXED agent-scope atomics (write-through
// stores + L2-bypass loads) -> no fences, no invalidates; U/xz stay L2-resident.
// Barrier counter relaxed; ordering via __syncthreads' vmcnt(0) drain.
// U persistent in VGPRs (loaded once); grid 128x256, 1 block/CU, 64KB LDS.
// GEMMs/embed/head unchanged from R6/R8 (proven). Footprint = proven 168,955,904 B.
#include <hip/hip_runtime.h>
#include <hip/hip_fp16.h>
#include <math.h>

#define NB   64
#define NS   256
#define ND   300
#define NDP  320
#define NH   512
#define N4H  2048

typedef _Float16 half8_t __attribute__((ext_vector_type(8)));
typedef float    f32x4_t __attribute__((ext_vector_type(4)));

// ---------- embedding: gather + fp16 convert + zero-pad K to 320 ----------
__global__ void embed_f16_kernel(const int* __restrict__ text,
                                 const float* __restrict__ emb,
                                 _Float16* __restrict__ x) {
  int idx = blockIdx.x * 256 + threadIdx.x;
  const int total = NB * NS * NDP;
  for (; idx < total; idx += gridDim.x * 256) {
    int bs = idx / NDP;
    int d  = idx - bs * NDP;
    x[idx] = (d < ND) ? (_Float16)emb[(size_t)text[bs] * ND + d] : (_Float16)0.f;
  }
}

// ---------- MFMA GEMM with in-LDS weight transpose (unchanged from R6) ----------
__global__ __launch_bounds__(256) void gemm_mfma_kernel(
    const _Float16* __restrict__ A, const float* __restrict__ W,
    const float* __restrict__ bias, __half* __restrict__ C,
    int M, int N, int K, int Kw) {
  __shared__ __align__(16) _Float16 as[128][40];
  __shared__ __align__(16) _Float16 ws16[128][40];
  __shared__ __align__(16) float    ws32[32][132];
  const int t = threadIdx.x;
  const int w = t >> 6;
  const int l = t & 63;
  const int lane16 = l & 15;
  const int kq = l >> 4;
  const int bm = blockIdx.y * 128;
  const int bn = blockIdx.x * 128;
  const int lr  = t >> 2;
  const int lsg = t & 3;
  const int wk  = t >> 3;
  const int wns = t & 7;
  const int rn  = t >> 1;
  const int rk0 = (t & 1) * 2;

  f32x4_t acc[2][8];
#pragma unroll
  for (int i = 0; i < 2; i++)
#pragma unroll
    for (int j = 0; j < 8; j++) acc[i][j] = (f32x4_t){0.f, 0.f, 0.f, 0.f};

  for (int k0 = 0; k0 < K; k0 += 32) {
#pragma unroll
    for (int h = 0; h < 2; h++) {
      int m = h * 64 + lr;
      *(uint4*)&as[m][lsg * 8] = *(const uint4*)(A + (size_t)(bm + m) * K + k0 + lsg * 8);
    }
    if (k0 + wk < Kw) {
#pragma unroll
      for (int i = 0; i < 4; i++)
        *(float4*)&ws32[wk][wns * 16 + i * 4] =
            *(const float4*)(W + (size_t)(k0 + wk) * N + bn + wns * 16 + i * 4);
    } else {
#pragma unroll
      for (int i = 0; i < 4; i++)
        *(float4*)&ws32[wk][wns * 16 + i * 4] = make_float4(0.f, 0.f, 0.f, 0.f);
    }
    __syncthreads();
#pragma unroll
    for (int g = 0; g < 2; g++) {
      int kqq = rk0 + g;
      half8_t hv;
#pragma unroll
      for (int jj = 0; jj < 8; jj++) hv[jj] = (_Float16)ws32[kqq * 8 + jj][rn];
      *(half8_t*)&ws16[rn][kqq * 8] = hv;
    }
    __syncthreads();
    half8_t afrag[2];
#pragma unroll
    for (int i = 0; i < 2; i++)
      afrag[i] = *(const half8_t*)&as[w * 32 + i * 16 + lane16][kq * 8];
#pragma unroll
    for (int j = 0; j < 8; j++) {
      half8_t bfrag = *(const half8_t*)&ws16[j * 16 + lane16][kq * 8];
#pragma unroll
      for (int i = 0; i < 2; i++)
        acc[i][j] = __builtin_amdgcn_mfma_f32_16x16x32_f16(afrag[i], bfrag, acc[i][j], 0, 0, 0);
    }
    __syncthreads();
  }
#pragma unroll
  for (int j = 0; j < 8; j++) {
    int col = bn + j * 16 + lane16;
    float bv = bias[col];
#pragma unroll
    for (int i = 0; i < 2; i++) {
      int rbase = bm + w * 32 + i * 16 + kq * 4;
#pragma unroll
      for (int r = 0; r < 4; r++)
        C[(size_t)(rbase + r) * N + col] = __float2half(acc[i][j][r] + bv);
    }
  }
}

// ---------- persistent bi-LSTM scan, LLC-native barrier ----------
// Grid MUST be 128 x 256. Block bi = dir*64 + cblk; owns h-cols [cblk*8,+8).
// h ping-pong buffers accessed ONLY via relaxed agent atomics (LLC). U slice
// 512x32 fp16 persistent in VGPRs. c/h state in registers.
__global__ __launch_bounds__(256, 1) void scan_persist_kernel(
    const __half* __restrict__ xzf, const __half* __restrict__ xzb,
    const float* __restrict__ Uf, const float* __restrict__ Ub,
    const int* __restrict__ text,
    __half* __restrict__ h0buf, __half* __restrict__ h1buf,
    int* __restrict__ cnt, int* __restrict__ abortf,
    __half* __restrict__ hs_out, float* __restrict__ hT_out) {
  __shared__ __align__(16) char lds[65536];
  __shared__ int s_brk;
  _Float16* s_h = (_Float16*)lds;   // [64][512] fp16, chunk-XOR swizzle
  float*    s_z = (float*)lds;      // [64][33] fp32 overlay (after MFMA reads)

  const int t    = threadIdx.x;
  const int bi   = blockIdx.x;
  const int dir  = bi >> 6;
  const int cblk = bi & 63;
  const int hc0  = cblk * 8;
  const __half* xz = dir ? xzb : xzf;
  const float* U = dir ? Ub : Uf;
  int* mycnt = cnt + dir * NS;

  const int w    = t >> 6;          // wave = m-tile (rows w*16..w*16+16)
  const int lane = t & 63;
  const int l16  = lane & 15;
  const int quad = lane >> 4;

  // persistent U B-frags: ufrag[kt][nt] = U[k=kt*32+quad*8+jj][col(nt,l16)] fp16
  half8_t ufrag[16][2];
#pragma unroll
  for (int nt = 0; nt < 2; nt++) {
    int c = nt * 16 + l16;
    int col = (c >> 3) * NH + hc0 + (c & 7);
#pragma unroll
    for (int kt = 0; kt < 16; kt++)
#pragma unroll
      for (int jj = 0; jj < 8; jj++)
        ufrag[kt][nt][jj] = (_Float16)U[(size_t)(kt * 32 + quad * 8 + jj) * N4H + col];
  }

  // LSTM state: thread owns (row = t>>2, col pair cp = t&3 -> j {2cp, 2cp+1})
  const int srow = t >> 2;
  const int scp  = t & 3;
  float c_st[2] = {0.f, 0.f}, h_st[2] = {0.f, 0.f};

  for (int s = 0; s < NS; s++) {
    const int tt = dir ? (NS - 1 - s) : s;
    __half* hw       = (s & 1) ? h1buf : h0buf;
    const __half* hr = (s & 1) ? h0buf : h1buf;
    f32x4_t acc[2] = {{0.f, 0.f, 0.f, 0.f}, {0.f, 0.f, 0.f, 0.f}};

    if (s > 0) {
      // stage h(s-1): 64 rows x 512 fp16 via 8B LLC loads; chunk ch at ch^row
      const unsigned long long* hr64 = (const unsigned long long*)hr;
#pragma unroll
      for (int i = 0; i < 32; i++) {
        int e   = i * 256 + t;        // 8B unit 0..8191
        int row = e >> 7;
        int hh  = e & 127;            // 8B unit within row (4 halves)
        int ch  = hh >> 1, hb = hh & 1;
        unsigned long long v = __hip_atomic_load(
            hr64 + row * 256 + dir * 128 + hh,
            __ATOMIC_RELAXED, __HIP_MEMORY_SCOPE_AGENT);
        *(unsigned long long*)(s_h + row * 512 + (ch ^ row) * 8 + hb * 4) = v;
      }
      __syncthreads();
#pragma unroll
      for (int kt = 0; kt < 16; kt++) {
        int r = w * 16 + l16;
        int chunk = (kt * 4 + quad) ^ r;
        half8_t af = *(const half8_t*)(s_h + r * 512 + chunk * 8);
        acc[0] = __builtin_amdgcn_mfma_f32_16x16x32_f16(af, ufrag[kt][0], acc[0], 0, 0, 0);
        acc[1] = __builtin_amdgcn_mfma_f32_16x16x32_f16(af, ufrag[kt][1], acc[1], 0, 0, 0);
      }
      __syncthreads();   // all s_h reads done before s_z overlay
    }

    // dump z = acc + xz into LDS z[64][33]
    {
      int row0 = w * 16 + quad * 4;
#pragma unroll
      for (int nt = 0; nt < 2; nt++) {
        int c = nt * 16 + l16;
        int g = c >> 3, j = c & 7;
#pragma unroll
        for (int r4 = 0; r4 < 4; r4++) {
          int row = row0 + r4;
          float xzv = __half2float(xz[((size_t)row * NS + tt) * N4H + g * NH + hc0 + j]);
          s_z[row * 33 + c] = acc[nt][r4] + xzv;
        }
      }
    }
    __syncthreads();

    // gate update: 2 adjacent states (j = 2cp, 2cp+1) per thread
    {
      float hn2[2];
      bool m = text[srow * NS + tt] != 0;
#pragma unroll
      for (int u = 0; u < 2; u++) {
        int j = scp * 2 + u;
        float zi = s_z[srow * 33 + j];
        float zf = s_z[srow * 33 + 8 + j];
        float zg = s_z[srow * 33 + 16 + j];
        float zo = s_z[srow * 33 + 24 + j];
        float ig = 1.f / (1.f + expf(-zi));
        float fg = 1.f / (1.f + expf(-zf));
        float gv = tanhf(zg);
        float og = 1.f / (1.f + expf(-zo));
        float cn = fg * c_st[u] + ig * gv;
        float hn = og * tanhf(cn);
        if (m) { c_st[u] = cn; h_st[u] = hn; }
        hn2[u] = h_st[u];
      }
      union { __half h[2]; unsigned u; } pk;
      pk.h[0] = __float2half(hn2[0]);
      pk.h[1] = __float2half(hn2[1]);
      // write-through (LLC) store of the packed pair
      __hip_atomic_store((unsigned*)hw + srow * 512 + dir * 256 + (hc0 >> 1) + scp,
                         pk.u, __ATOMIC_RELAXED, __HIP_MEMORY_SCOPE_AGENT);
      if (hs_out)
        *((unsigned*)hs_out + ((size_t)srow * NS + tt) * 512 + dir * 256 + (hc0 >> 1) + scp) = pk.u;
      if (hT_out && s == NS - 1) {
        hT_out[(size_t)srow * 1024 + dir * NH + hc0 + scp * 2]     = hn2[0];
        hT_out[(size_t)srow * 1024 + dir * NH + hc0 + scp * 2 + 1] = hn2[1];
      }
    }

    if (s < NS - 1) {
      __syncthreads();      // drains vmcnt(0): h stores LLC-visible; s_z reads done
      if (t == 0) {
        __hip_atomic_fetch_add(mycnt + s, 1, __ATOMIC_RELAXED, __HIP_MEMORY_SCOPE_AGENT);
        int it = 0;
        while (__hip_atomic_load(mycnt + s, __ATOMIC_RELAXED, __HIP_MEMORY_SCOPE_AGENT) < 64) {
          __builtin_amdgcn_s_sleep(2);
          if (((++it) & 1023) == 0) {
            if (it > 200000)
              __hip_atomic_store(abortf, 1, __ATOMIC_RELAXED, __HIP_MEMORY_SCOPE_AGENT);
            if (__hip_atomic_load(abortf, __ATOMIC_RELAXED, __HIP_MEMORY_SCOPE_AGENT)) break;
          }
        }
        s_brk = __hip_atomic_load(abortf, __ATOMIC_RELAXED, __HIP_MEMORY_SCOPE_AGENT);
      }
      __syncthreads();      // barrier passed; also protects s_h rewrite next iter
      if (s_brk) return;    // fast-fail instead of hang
    }
  }
}

// ---------- fp32 SMEM GEMM (head only) ----------
template <int ACT>
__global__ __launch_bounds__(256) void gemm_kernel(
    const float* __restrict__ A, const float* __restrict__ W,
    const float* __restrict__ bias, float* __restrict__ C,
    int M, int N, int K) {
  __shared__ __align__(16) float As[8][128];
  __shared__ __align__(16) float Bs[8][128];
  const int t  = threadIdx.x;
  const int bn = blockIdx.x * 128;
  const int bm = blockIdx.y * 128;
  const int tx = t & 15, ty = t >> 4;
  const int lm  = t >> 1;
  const int lk4 = (t & 1) * 4;
  const int lbk = t >> 5;
  const int lbn = (t & 31) * 4;
  float acc[8][8];
#pragma unroll
  for (int i = 0; i < 8; i++)
#pragma unroll
    for (int j = 0; j < 8; j++) acc[i][j] = 0.f;

  for (int k0 = 0; k0 < K; k0 += 8) {
#pragma unroll
    for (int i = 0; i < 4; i++) {
      int k = k0 + lk4 + i;
      int m = bm + lm;
      float v = 0.f;
      if (k < K && m < M) v = A[(size_t)m * K + k];
      As[lk4 + i][lm] = v;
    }
    {
      int k = k0 + lbk;
      float4 v = make_float4(0.f, 0.f, 0.f, 0.f);
      if (k < K) v = *(const float4*)(W + (size_t)k * N + bn + lbn);
      *(float4*)(&Bs[lbk][lbn]) = v;
    }
    __syncthreads();
#pragma unroll
    for (int kk = 0; kk < 8; kk++) {
      float a[8], b[8];
      *(float4*)(a)     = *(const float4*)(&As[kk][ty * 8]);
      *(float4*)(a + 4) = *(const float4*)(&As[kk][ty * 8 + 4]);
      *(float4*)(b)     = *(const float4*)(&Bs[kk][tx * 8]);
      *(float4*)(b + 4) = *(const float4*)(&Bs[kk][tx * 8 + 4]);
#pragma unroll
      for (int i = 0; i < 8; i++)
#pragma unroll
        for (int j = 0; j < 8; j++) acc[i][j] += a[i] * b[j];
    }
    __syncthreads();
  }
  float4 bv0 = *(const float4*)(bias + bn + tx * 8);
  float4 bv1 = *(const float4*)(bias + bn + tx * 8 + 4);
#pragma unroll
  for (int i = 0; i < 8; i++) {
    int m = bm + ty * 8 + i;
    if (m >= M) continue;
    float4 o0, o1;
    o0.x = acc[i][0] + bv0.x; o0.y = acc[i][1] + bv0.y;
    o0.z = acc[i][2] + bv0.z; o0.w = acc[i][3] + bv0.w;
    o1.x = acc[i][4] + bv1.x; o1.y = acc[i][5] + bv1.y;
    o1.z = acc[i][6] + bv1.z; o1.w = acc[i][7] + bv1.w;
    if (ACT == 1) {
      o0.x = o0.x >= 0.f ? o0.x : 0.2f * o0.x;  o0.y = o0.y >= 0.f ? o0.y : 0.2f * o0.y;
      o0.z = o0.z >= 0.f ? o0.z : 0.2f * o0.z;  o0.w = o0.w >= 0.f ? o0.w : 0.2f * o0.w;
      o1.x = o1.x >= 0.f ? o1.x : 0.2f * o1.x;  o1.y = o1.y >= 0.f ? o1.y : 0.2f * o1.y;
      o1.z = o1.z >= 0.f ? o1.z : 0.2f * o1.z;  o1.w = o1.w >= 0.f ? o1.w : 0.2f * o1.w;
    }
    *(float4*)(C + (size_t)m * N + bn + tx * 8)     = o0;
    *(float4*)(C + (size_t)m * N + bn + tx * 8 + 4) = o1;
  }
}

__global__ void final_kernel(const float* __restrict__ a1, const float* __restrict__ w,
                             const float* __restrict__ bias, float* __restrict__ out) {
  const int b = blockIdx.x, t = threadIdx.x;
  float v = a1[b * 256 + t] * w[t];
#pragma unroll
  for (int off = 32; off > 0; off >>= 1) v += __shfl_down(v, off, 64);
  __shared__ float red[4];
  if ((t & 63) == 0) red[t >> 6] = v;
  __syncthreads();
  if (t == 0) out[b] = (red[0] + red[1]) + (red[2] + red[3]) + bias[0];
}

extern "C" void kernel_launch(void* const* d_in, const int* in_sizes, int n_in,
                              void* d_out, int out_size, void* d_ws, size_t ws_size,
                              hipStream_t stream) {
  const int*   text = (const int*)  d_in[0];
  const float* emb  = (const float*)d_in[1];
  const float* W0f  = (const float*)d_in[2];
  const float* U0f  = (const float*)d_in[3];
  const float* b0f  = (const float*)d_in[4];
  const float* W0b  = (const float*)d_in[5];
  const float* U0b  = (const float*)d_in[6];
  const float* b0b  = (const float*)d_in[7];
  const float* W1f  = (const float*)d_in[8];
  const float* U1f  = (const float*)d_in[9];
  const float* b1f  = (const float*)d_in[10];
  const float* W1b  = (const float*)d_in[11];
  const float* U1b  = (const float*)d_in[12];
  const float* b1b  = (const float*)d_in[13];
  const float* d0w  = (const float*)d_in[14];
  const float* d0b  = (const float*)d_in[15];
  const float* d1w  = (const float*)d_in[16];
  const float* d1b  = (const float*)d_in[17];
  const float* d2w  = (const float*)d_in[18];
  const float* d2b  = (const float*)d_in[19];
  float* out = (float*)d_out;

  // workspace carve: identical to R4/R6/R8 proven footprint (168,955,904 B)
  char* p = (char*)d_ws;
  __half* xzA = (__half*)p;  p += (size_t)NB * NS * N4H * 2;
  __half* xzB = (__half*)p;  p += (size_t)NB * NS * N4H * 2;
  char* region1 = p;         p += (size_t)NB * NS * 1024 * 2;
  _Float16* x_emb = (_Float16*)region1;   // dead before hs0 written
  __half*   hs0   = (__half*)region1;
  __half* hp0  = (__half*)p;  p += 64 * 1024 * 2;
  __half* hp1  = (__half*)p;  p += 64 * 1024 * 2;
  int*    cnt  = (int*)p;     p += 64 * 1024 * 4;   // old cbuf slot: counters+abort
  float*  feat = (float*)p;   p += 64 * 1024 * 4;
  float*  a0   = (float*)p;   p += 64 * 512 * 4;
  float*  a1   = (float*)p;   p += 64 * 256 * 4;
  int* cnt0   = cnt;          // layer0: [dir*256 + s]
  int* cnt1   = cnt + 512;    // layer1
  int* abortf = cnt + 1024;

  hipMemsetAsync(cnt, 0, 1025 * sizeof(int), stream);
  hipLaunchKernelGGL(embed_f16_kernel, dim3(4096), dim3(256), 0, stream, text, emb, x_emb);

  dim3 gmf(16, 128);
  hipLaunchKernelGGL(gemm_mfma_kernel, gmf, dim3(256), 0, stream, x_emb, W0f, b0f, xzA, 16384, N4H, NDP, ND);
  hipLaunchKernelGGL(gemm_mfma_kernel, gmf, dim3(256), 0, stream, x_emb, W0b, b0b, xzB, 16384, N4H, NDP, ND);

  hipLaunchKernelGGL(scan_persist_kernel, dim3(128), dim3(256), 0, stream,
                     xzA, xzB, U0f, U0b, text, hp0, hp1, cnt0, abortf,
                     hs0, (float*)nullptr);

  hipLaunchKernelGGL(gemm_mfma_kernel, gmf, dim3(256), 0, stream, (const _Float16*)hs0, W1f, b1f, xzA, 16384, N4H, 1024, 1024);
  hipLaunchKernelGGL(gemm_mfma_kernel, gmf, dim3(256), 0, stream, (const _Float16*)hs0, W1b, b1b, xzB, 16384, N4H, 1024, 1024);

  hipLaunchKernelGGL(scan_persist_kernel, dim3(128), dim3(256), 0, stream,
                     xzA, xzB, U1f, U1b, text, hp0, hp1, cnt1, abortf,
                     (__half*)nullptr, feat);

  gemm_kernel<1><<<dim3(4, 1), dim3(256), 0, stream>>>(feat, d0w, d0b, a0, 64, 512, 1024);
  gemm_kernel<1><<<dim3(2, 1), dim3(256), 0, stream>>>(a0, d1w, d1b, a1, 64, 256, 512);
  hipLaunchKernelGGL(final_kernel, dim3(64), dim3(256), 0, stream, a1, d2w, d2b, out);
}

// Round 10
// 6546.199 us; speedup vs baseline: 1.0833x; 1.0833x over previous
//
// R10: ring-buffer persistent scan. R9 post-mortem: agent-scope atomic LOADS
// bypass L2 -> 8192x8B uncached transactions/step/block = 697MB FETCH, 12us/step.
// Fix: h(s) written to a per-step ring slot (layer0 ring == hs0 output buffer;
// layer1 reuses same region, dead after GEMMs). Stores stay relaxed write-through
// (LLC, proven R9); loads become plain cached uint4 (slot never previously
// cached in this kernel + dispatch-boundary invalidate => no stale L2 hits).
// 32 blocks/dir (16 h-cols, ufrag 64 VGPR, LDS 83KB). Barrier logic = R9 verbatim.
// GEMMs/embed/head unchanged. Footprint = proven 168,955,904 B.
#include <hip/hip_runtime.h>
#include <hip/hip_fp16.h>
#include <math.h>

#define NB   64
#define NS   256
#define ND   300
#define NDP  320
#define NH   512
#define N4H  2048

typedef _Float16 half8_t __attribute__((ext_vector_type(8)));
typedef float    f32x4_t __attribute__((ext_vector_type(4)));

// ---------- embedding: gather + fp16 convert + zero-pad K to 320 ----------
__global__ void embed_f16_kernel(const int* __restrict__ text,
                                 const float* __restrict__ emb,
                                 _Float16* __restrict__ x) {
  int idx = blockIdx.x * 256 + threadIdx.x;
  const int total = NB * NS * NDP;
  for (; idx < total; idx += gridDim.x * 256) {
    int bs = idx / NDP;
    int d  = idx - bs * NDP;
    x[idx] = (d < ND) ? (_Float16)emb[(size_t)text[bs] * ND + d] : (_Float16)0.f;
  }
}

// ---------- MFMA GEMM with in-LDS weight transpose (unchanged from R6) ----------
__global__ __launch_bounds__(256) void gemm_mfma_kernel(
    const _Float16* __restrict__ A, const float* __restrict__ W,
    const float* __restrict__ bias, __half* __restrict__ C,
    int M, int N, int K, int Kw) {
  __shared__ __align__(16) _Float16 as[128][40];
  __shared__ __align__(16) _Float16 ws16[128][40];
  __shared__ __align__(16) float    ws32[32][132];
  const int t = threadIdx.x;
  const int w = t >> 6;
  const int l = t & 63;
  const int lane16 = l & 15;
  const int kq = l >> 4;
  const int bm = blockIdx.y * 128;
  const int bn = blockIdx.x * 128;
  const int lr  = t >> 2;
  const int lsg = t & 3;
  const int wk  = t >> 3;
  const int wns = t & 7;
  const int rn  = t >> 1;
  const int rk0 = (t & 1) * 2;

  f32x4_t acc[2][8];
#pragma unroll
  for (int i = 0; i < 2; i++)
#pragma unroll
    for (int j = 0; j < 8; j++) acc[i][j] = (f32x4_t){0.f, 0.f, 0.f, 0.f};

  for (int k0 = 0; k0 < K; k0 += 32) {
#pragma unroll
    for (int h = 0; h < 2; h++) {
      int m = h * 64 + lr;
      *(uint4*)&as[m][lsg * 8] = *(const uint4*)(A + (size_t)(bm + m) * K + k0 + lsg * 8);
    }
    if (k0 + wk < Kw) {
#pragma unroll
      for (int i = 0; i < 4; i++)
        *(float4*)&ws32[wk][wns * 16 + i * 4] =
            *(const float4*)(W + (size_t)(k0 + wk) * N + bn + wns * 16 + i * 4);
    } else {
#pragma unroll
      for (int i = 0; i < 4; i++)
        *(float4*)&ws32[wk][wns * 16 + i * 4] = make_float4(0.f, 0.f, 0.f, 0.f);
    }
    __syncthreads();
#pragma unroll
    for (int g = 0; g < 2; g++) {
      int kqq = rk0 + g;
      half8_t hv;
#pragma unroll
      for (int jj = 0; jj < 8; jj++) hv[jj] = (_Float16)ws32[kqq * 8 + jj][rn];
      *(half8_t*)&ws16[rn][kqq * 8] = hv;
    }
    __syncthreads();
    half8_t afrag[2];
#pragma unroll
    for (int i = 0; i < 2; i++)
      afrag[i] = *(const half8_t*)&as[w * 32 + i * 16 + lane16][kq * 8];
#pragma unroll
    for (int j = 0; j < 8; j++) {
      half8_t bfrag = *(const half8_t*)&ws16[j * 16 + lane16][kq * 8];
#pragma unroll
      for (int i = 0; i < 2; i++)
        acc[i][j] = __builtin_amdgcn_mfma_f32_16x16x32_f16(afrag[i], bfrag, acc[i][j], 0, 0, 0);
    }
    __syncthreads();
  }
#pragma unroll
  for (int j = 0; j < 8; j++) {
    int col = bn + j * 16 + lane16;
    float bv = bias[col];
#pragma unroll
    for (int i = 0; i < 2; i++) {
      int rbase = bm + w * 32 + i * 16 + kq * 4;
#pragma unroll
      for (int r = 0; r < 4; r++)
        C[(size_t)(rbase + r) * N + col] = __float2half(acc[i][j][r] + bv);
    }
  }
}

// ---------- persistent bi-LSTM scan with per-step ring slots ----------
// Grid MUST be 64 x 256. Block bi = dir*32 + cblk; owns h-cols [cblk*16,+16)
// (64 z-cols, gate g = n-tile). ring: (64*NS, 1024) fp16; slot tt holds h at
// time tt (fwd cols [0,512), bwd [512,1024)). Writes: relaxed agent 8B
// write-through. Reads: plain cached uint4 (each slot read once per kernel).
__global__ __launch_bounds__(256, 1) void scan_ring_kernel(
    const __half* __restrict__ xzf, const __half* __restrict__ xzb,
    const float* __restrict__ Uf, const float* __restrict__ Ub,
    const int* __restrict__ text,
    __half* ring,
    int* cnt, int* abortf,
    float* __restrict__ hT_out) {
  __shared__ __align__(16) _Float16 s_h[64 * 512];   // 64KB h tile, XOR swizzle
  __shared__ __align__(16) float    s_z[64 * 68];    // 17.4KB z
  __shared__ int s_brk;

  const int t    = threadIdx.x;
  const int bi   = blockIdx.x;
  const int dir  = bi >> 5;
  const int cblk = bi & 31;
  const int hc0  = cblk * 16;
  const __half* xz = dir ? xzb : xzf;
  const float* U = dir ? Ub : Uf;
  int* mycnt = cnt + dir * NS;

  const int w    = t >> 6;          // wave = m-tile (rows w*16..w*16+16)
  const int lane = t & 63;
  const int l16  = lane & 15;
  const int quad = lane >> 4;

  // persistent U B-frags: ufrag[kt][nt][jj] = U[kt*32+quad*8+jj][nt*512+hc0+l16]
  half8_t ufrag[16][4];
#pragma unroll
  for (int nt = 0; nt < 4; nt++) {
    int col = nt * NH + hc0 + l16;
#pragma unroll
    for (int kt = 0; kt < 16; kt++)
#pragma unroll
      for (int jj = 0; jj < 8; jj++)
        ufrag[kt][nt][jj] = (_Float16)U[(size_t)(kt * 32 + quad * 8 + jj) * N4H + col];
  }

  // LSTM state: thread owns row = t>>2, cols jb..jb+3 (jb = (t&3)*4)
  const int srow = t >> 2;
  const int jb   = (t & 3) * 4;
  float c_st[4] = {0.f, 0.f, 0.f, 0.f}, h_st[4] = {0.f, 0.f, 0.f, 0.f};

  for (int s = 0; s < NS; s++) {
    const int tt = dir ? (NS - 1 - s) : s;
    f32x4_t acc[4] = {{0.f,0.f,0.f,0.f},{0.f,0.f,0.f,0.f},{0.f,0.f,0.f,0.f},{0.f,0.f,0.f,0.f}};

    if (s > 0) {
      const int ttp = dir ? (tt + 1) : (tt - 1);   // slot holding h(s-1)
      // stage h(s-1): 64 rows x 512 fp16 via plain cached uint4; chunk ch at ch^row
#pragma unroll
      for (int i = 0; i < 16; i++) {
        int e   = i * 256 + t;        // 16B chunk id 0..4095
        int row = e >> 6;
        int ch  = e & 63;
        *(uint4*)(s_h + row * 512 + (ch ^ row) * 8) =
            *(const uint4*)(ring + ((size_t)row * NS + ttp) * 1024 + dir * NH + ch * 8);
      }
      __syncthreads();
      const int r = w * 16 + l16;
#pragma unroll
      for (int kt = 0; kt < 16; kt++) {
        int chunk = (kt * 4 + quad) ^ r;
        half8_t af = *(const half8_t*)(s_h + r * 512 + chunk * 8);
#pragma unroll
        for (int nt = 0; nt < 4; nt++)
          acc[nt] = __builtin_amdgcn_mfma_f32_16x16x32_f16(af, ufrag[kt][nt], acc[nt], 0, 0, 0);
      }
    }

    // dump z = acc + xz into s_z[64][68]; gate g == n-tile nt
    {
      int row0 = w * 16 + quad * 4;
#pragma unroll
      for (int nt = 0; nt < 4; nt++) {
#pragma unroll
        for (int r4 = 0; r4 < 4; r4++) {
          int row = row0 + r4;
          float xzv = __half2float(xz[((size_t)row * NS + tt) * N4H + nt * NH + hc0 + l16]);
          s_z[row * 68 + nt * 16 + l16] = acc[nt][r4] + xzv;
        }
      }
    }
    __syncthreads();

    // gate update: 4 states per thread (row srow, cols jb..jb+3)
    {
      bool m = text[srow * NS + tt] != 0;
      float4 zi = *(const float4*)&s_z[srow * 68 + 0  + jb];
      float4 zf = *(const float4*)&s_z[srow * 68 + 16 + jb];
      float4 zg = *(const float4*)&s_z[srow * 68 + 32 + jb];
      float4 zo = *(const float4*)&s_z[srow * 68 + 48 + jb];
      float ziv[4] = {zi.x, zi.y, zi.z, zi.w};
      float zfv[4] = {zf.x, zf.y, zf.z, zf.w};
      float zgv[4] = {zg.x, zg.y, zg.z, zg.w};
      float zov[4] = {zo.x, zo.y, zo.z, zo.w};
      union { __half h[4]; unsigned long long u; } pk;
#pragma unroll
      for (int u = 0; u < 4; u++) {
        float ig = 1.f / (1.f + expf(-ziv[u]));
        float fg = 1.f / (1.f + expf(-zfv[u]));
        float gv = tanhf(zgv[u]);
        float og = 1.f / (1.f + expf(-zov[u]));
        float cn = fg * c_st[u] + ig * gv;
        float hn = og * tanhf(cn);
        if (m) { c_st[u] = cn; h_st[u] = hn; }
        pk.h[u] = __float2half(h_st[u]);
      }
      // write-through (LLC) 8B store into ring slot tt
      size_t haddr = ((size_t)srow * NS + tt) * 1024 + dir * NH + hc0 + jb;
      __hip_atomic_store((unsigned long long*)ring + (haddr >> 2), pk.u,
                         __ATOMIC_RELAXED, __HIP_MEMORY_SCOPE_AGENT);
      if (hT_out && s == NS - 1) {
#pragma unroll
        for (int u = 0; u < 4; u++)
          hT_out[(size_t)srow * 1024 + dir * NH + hc0 + jb + u] = h_st[u];
      }
    }

    if (s < NS - 1) {
      __syncthreads();      // drains vmcnt(0): ring stores LLC-visible; s_z reads done
      if (t == 0) {
        __hip_atomic_fetch_add(mycnt + s, 1, __ATOMIC_RELAXED, __HIP_MEMORY_SCOPE_AGENT);
        int it = 0;
        while (__hip_atomic_load(mycnt + s, __ATOMIC_RELAXED, __HIP_MEMORY_SCOPE_AGENT) < 32) {
          __builtin_amdgcn_s_sleep(2);
          if (((++it) & 1023) == 0) {
            if (it > 200000)
              __hip_atomic_store(abortf, 1, __ATOMIC_RELAXED, __HIP_MEMORY_SCOPE_AGENT);
            if (__hip_atomic_load(abortf, __ATOMIC_RELAXED, __HIP_MEMORY_SCOPE_AGENT)) break;
          }
        }
        s_brk = __hip_atomic_load(abortf, __ATOMIC_RELAXED, __HIP_MEMORY_SCOPE_AGENT);
      }
      __syncthreads();      // barrier passed; also protects s_h rewrite next iter
      if (s_brk) return;    // fast-fail instead of hang
    }
  }
}

// ---------- fp32 SMEM GEMM (head only) ----------
template <int ACT>
__global__ __launch_bounds__(256) void gemm_kernel(
    const float* __restrict__ A, const float* __restrict__ W,
    const float* __restrict__ bias, float* __restrict__ C,
    int M, int N, int K) {
  __shared__ __align__(16) float As[8][128];
  __shared__ __align__(16) float Bs[8][128];
  const int t  = threadIdx.x;
  const int bn = blockIdx.x * 128;
  const int bm = blockIdx.y * 128;
  const int tx = t & 15, ty = t >> 4;
  const int lm  = t >> 1;
  const int lk4 = (t & 1) * 4;
  const int lbk = t >> 5;
  const int lbn = (t & 31) * 4;
  float acc[8][8];
#pragma unroll
  for (int i = 0; i < 8; i++)
#pragma unroll
    for (int j = 0; j < 8; j++) acc[i][j] = 0.f;

  for (int k0 = 0; k0 < K; k0 += 8) {
#pragma unroll
    for (int i = 0; i < 4; i++) {
      int k = k0 + lk4 + i;
      int m = bm + lm;
      float v = 0.f;
      if (k < K && m < M) v = A[(size_t)m * K + k];
      As[lk4 + i][lm] = v;
    }
    {
      int k = k0 + lbk;
      float4 v = make_float4(0.f, 0.f, 0.f, 0.f);
      if (k < K) v = *(const float4*)(W + (size_t)k * N + bn + lbn);
      *(float4*)(&Bs[lbk][lbn]) = v;
    }
    __syncthreads();
#pragma unroll
    for (int kk = 0; kk < 8; kk++) {
      float a[8], b[8];
      *(float4*)(a)     = *(const float4*)(&As[kk][ty * 8]);
      *(float4*)(a + 4) = *(const float4*)(&As[kk][ty * 8 + 4]);
      *(float4*)(b)     = *(const float4*)(&Bs[kk][tx * 8]);
      *(float4*)(b + 4) = *(const float4*)(&Bs[kk][tx * 8 + 4]);
#pragma unroll
      for (int i = 0; i < 8; i++)
#pragma unroll
        for (int j = 0; j < 8; j++) acc[i][j] += a[i] * b[j];
    }
    __syncthreads();
  }
  float4 bv0 = *(const float4*)(bias + bn + tx * 8);
  float4 bv1 = *(const float4*)(bias + bn + tx * 8 + 4);
#pragma unroll
  for (int i = 0; i < 8; i++) {
    int m = bm + ty * 8 + i;
    if (m >= M) continue;
    float4 o0, o1;
    o0.x = acc[i][0] + bv0.x; o0.y = acc[i][1] + bv0.y;
    o0.z = acc[i][2] + bv0.z; o0.w = acc[i][3] + bv0.w;
    o1.x = acc[i][4] + bv1.x; o1.y = acc[i][5] + bv1.y;
    o1.z = acc[i][6] + bv1.z; o1.w = acc[i][7] + bv1.w;
    if (ACT == 1) {
      o0.x = o0.x >= 0.f ? o0.x : 0.2f * o0.x;  o0.y = o0.y >= 0.f ? o0.y : 0.2f * o0.y;
      o0.z = o0.z >= 0.f ? o0.z : 0.2f * o0.z;  o0.w = o0.w >= 0.f ? o0.w : 0.2f * o0.w;
      o1.x = o1.x >= 0.f ? o1.x : 0.2f * o1.x;  o1.y = o1.y >= 0.f ? o1.y : 0.2f * o1.y;
      o1.z = o1.z >= 0.f ? o1.z : 0.2f * o1.z;  o1.w = o1.w >= 0.f ? o1.w : 0.2f * o1.w;
    }
    *(float4*)(C + (size_t)m * N + bn + tx * 8)     = o0;
    *(float4*)(C + (size_t)m * N + bn + tx * 8 + 4) = o1;
  }
}

__global__ void final_kernel(const float* __restrict__ a1, const float* __restrict__ w,
                             const float* __restrict__ bias, float* __restrict__ out) {
  const int b = blockIdx.x, t = threadIdx.x;
  float v = a1[b * 256 + t] * w[t];
#pragma unroll
  for (int off = 32; off > 0; off >>= 1) v += __shfl_down(v, off, 64);
  __shared__ float red[4];
  if ((t & 63) == 0) red[t >> 6] = v;
  __syncthreads();
  if (t == 0) out[b] = (red[0] + red[1]) + (red[2] + red[3]) + bias[0];
}

extern "C" void kernel_launch(void* const* d_in, const int* in_sizes, int n_in,
                              void* d_out, int out_size, void* d_ws, size_t ws_size,
                              hipStream_t stream) {
  const int*   text = (const int*)  d_in[0];
  const float* emb  = (const float*)d_in[1];
  const float* W0f  = (const float*)d_in[2];
  const float* U0f  = (const float*)d_in[3];
  const float* b0f  = (const float*)d_in[4];
  const float* W0b  = (const float*)d_in[5];
  const float* U0b  = (const float*)d_in[6];
  const float* b0b  = (const float*)d_in[7];
  const float* W1f  = (const float*)d_in[8];
  const float* U1f  = (const float*)d_in[9];
  const float* b1f  = (const float*)d_in[10];
  const float* W1b  = (const float*)d_in[11];
  const float* U1b  = (const float*)d_in[12];
  const float* b1b  = (const float*)d_in[13];
  const float* d0w  = (const float*)d_in[14];
  const float* d0b  = (const float*)d_in[15];
  const float* d1w  = (const float*)d_in[16];
  const float* d1b  = (const float*)d_in[17];
  const float* d2w  = (const float*)d_in[18];
  const float* d2b  = (const float*)d_in[19];
  float* out = (float*)d_out;

  // workspace carve: identical to R4/R6/R8/R9 proven footprint (168,955,904 B)
  char* p = (char*)d_ws;
  __half* xzA = (__half*)p;  p += (size_t)NB * NS * N4H * 2;
  __half* xzB = (__half*)p;  p += (size_t)NB * NS * N4H * 2;
  char* region1 = p;         p += (size_t)NB * NS * 1024 * 2;
  _Float16* x_emb = (_Float16*)region1;   // dead before hs0 written
  __half*   hs0   = (__half*)region1;     // layer-0 ring == hs output; layer-1 ring reuses
  __half* hp0  = (__half*)p;  p += 64 * 1024 * 2;   // unused (carve kept identical)
  __half* hp1  = (__half*)p;  p += 64 * 1024 * 2;   // unused
  int*    cnt  = (int*)p;     p += 64 * 1024 * 4;   // barrier counters + abort
  float*  feat = (float*)p;   p += 64 * 1024 * 4;
  float*  a0   = (float*)p;   p += 64 * 512 * 4;
  float*  a1   = (float*)p;   p += 64 * 256 * 4;
  (void)hp0; (void)hp1;
  int* cnt0   = cnt;          // layer0: [dir*256 + s]
  int* cnt1   = cnt + 512;    // layer1
  int* abortf = cnt + 1024;

  hipMemsetAsync(cnt, 0, 1025 * sizeof(int), stream);
  hipLaunchKernelGGL(embed_f16_kernel, dim3(4096), dim3(256), 0, stream, text, emb, x_emb);

  dim3 gmf(16, 128);
  hipLaunchKernelGGL(gemm_mfma_kernel, gmf, dim3(256), 0, stream, x_emb, W0f, b0f, xzA, 16384, N4H, NDP, ND);
  hipLaunchKernelGGL(gemm_mfma_kernel, gmf, dim3(256), 0, stream, x_emb, W0b, b0b, xzB, 16384, N4H, NDP, ND);

  hipLaunchKernelGGL(scan_ring_kernel, dim3(64), dim3(256), 0, stream,
                     xzA, xzB, U0f, U0b, text, hs0, cnt0, abortf, (float*)nullptr);

  hipLaunchKernelGGL(gemm_mfma_kernel, gmf, dim3(256), 0, stream, (const _Float16*)hs0, W1f, b1f, xzA, 16384, N4H, 1024, 1024);
  hipLaunchKernelGGL(gemm_mfma_kernel, gmf, dim3(256), 0, stream, (const _Float16*)hs0, W1b, b1b, xzB, 16384, N4H, 1024, 1024);

  // layer-1 ring reuses region1 (hs0 dead after the two GEMMs above)
  hipLaunchKernelGGL(scan_ring_kernel, dim3(64), dim3(256), 0, stream,
                     xzA, xzB, U1f, U1b, text, hs0, cnt1, abortf, feat);

  gemm_kernel<1><<<dim3(4, 1), dim3(256), 0, stream>>>(feat, d0w, d0b, a0, 64, 512, 1024);
  gemm_kernel<1><<<dim3(2, 1), dim3(256), 0, stream>>>(a0, d1w, d1b, a1, 64, 256, 512);
  hipLaunchKernelGGL(final_kernel, dim3(64), dim3(256), 0, stream, a1, d2w, d2b, out);
}

// Round 11
// 5452.047 us; speedup vs baseline: 1.3007x; 1.2007x over previous
//
// R11: store/load-only barrier (R10 post-mortem: fetch_add + 63 pollers on one
// LLC line = serialized RMW storm ~ the unexplained ~7us/step). Arrival =
// per-block monotonic flag store (no RMW); detect = one 64-lane coalesced load
// of all 32 flags + __all. xz loads prefetched before the barrier drain.
// Ring staging / MFMA / gates / GEMMs / carve identical to R10 (proven).
#include <hip/hip_runtime.h>
#include <hip/hip_fp16.h>
#include <math.h>

#define NB   64
#define NS   256
#define ND   300
#define NDP  320
#define NH   512
#define N4H  2048

typedef _Float16 half8_t __attribute__((ext_vector_type(8)));
typedef float    f32x4_t __attribute__((ext_vector_type(4)));

// ---------- embedding: gather + fp16 convert + zero-pad K to 320 ----------
__global__ void embed_f16_kernel(const int* __restrict__ text,
                                 const float* __restrict__ emb,
                                 _Float16* __restrict__ x) {
  int idx = blockIdx.x * 256 + threadIdx.x;
  const int total = NB * NS * NDP;
  for (; idx < total; idx += gridDim.x * 256) {
    int bs = idx / NDP;
    int d  = idx - bs * NDP;
    x[idx] = (d < ND) ? (_Float16)emb[(size_t)text[bs] * ND + d] : (_Float16)0.f;
  }
}

// ---------- MFMA GEMM with in-LDS weight transpose (unchanged from R6) ----------
__global__ __launch_bounds__(256) void gemm_mfma_kernel(
    const _Float16* __restrict__ A, const float* __restrict__ W,
    const float* __restrict__ bias, __half* __restrict__ C,
    int M, int N, int K, int Kw) {
  __shared__ __align__(16) _Float16 as[128][40];
  __shared__ __align__(16) _Float16 ws16[128][40];
  __shared__ __align__(16) float    ws32[32][132];
  const int t = threadIdx.x;
  const int w = t >> 6;
  const int l = t & 63;
  const int lane16 = l & 15;
  const int kq = l >> 4;
  const int bm = blockIdx.y * 128;
  const int bn = blockIdx.x * 128;
  const int lr  = t >> 2;
  const int lsg = t & 3;
  const int wk  = t >> 3;
  const int wns = t & 7;
  const int rn  = t >> 1;
  const int rk0 = (t & 1) * 2;

  f32x4_t acc[2][8];
#pragma unroll
  for (int i = 0; i < 2; i++)
#pragma unroll
    for (int j = 0; j < 8; j++) acc[i][j] = (f32x4_t){0.f, 0.f, 0.f, 0.f};

  for (int k0 = 0; k0 < K; k0 += 32) {
#pragma unroll
    for (int h = 0; h < 2; h++) {
      int m = h * 64 + lr;
      *(uint4*)&as[m][lsg * 8] = *(const uint4*)(A + (size_t)(bm + m) * K + k0 + lsg * 8);
    }
    if (k0 + wk < Kw) {
#pragma unroll
      for (int i = 0; i < 4; i++)
        *(float4*)&ws32[wk][wns * 16 + i * 4] =
            *(const float4*)(W + (size_t)(k0 + wk) * N + bn + wns * 16 + i * 4);
    } else {
#pragma unroll
      for (int i = 0; i < 4; i++)
        *(float4*)&ws32[wk][wns * 16 + i * 4] = make_float4(0.f, 0.f, 0.f, 0.f);
    }
    __syncthreads();
#pragma unroll
    for (int g = 0; g < 2; g++) {
      int kqq = rk0 + g;
      half8_t hv;
#pragma unroll
      for (int jj = 0; jj < 8; jj++) hv[jj] = (_Float16)ws32[kqq * 8 + jj][rn];
      *(half8_t*)&ws16[rn][kqq * 8] = hv;
    }
    __syncthreads();
    half8_t afrag[2];
#pragma unroll
    for (int i = 0; i < 2; i++)
      afrag[i] = *(const half8_t*)&as[w * 32 + i * 16 + lane16][kq * 8];
#pragma unroll
    for (int j = 0; j < 8; j++) {
      half8_t bfrag = *(const half8_t*)&ws16[j * 16 + lane16][kq * 8];
#pragma unroll
      for (int i = 0; i < 2; i++)
        acc[i][j] = __builtin_amdgcn_mfma_f32_16x16x32_f16(afrag[i], bfrag, acc[i][j], 0, 0, 0);
    }
    __syncthreads();
  }
#pragma unroll
  for (int j = 0; j < 8; j++) {
    int col = bn + j * 16 + lane16;
    float bv = bias[col];
#pragma unroll
    for (int i = 0; i < 2; i++) {
      int rbase = bm + w * 32 + i * 16 + kq * 4;
#pragma unroll
      for (int r = 0; r < 4; r++)
        C[(size_t)(rbase + r) * N + col] = __float2half(acc[i][j][r] + bv);
    }
  }
}

// ---------- persistent bi-LSTM scan: ring slots + flag barrier ----------
// Grid MUST be 64 x 256. Block bi = dir*32 + cblk; owns h-cols [cblk*16,+16)
// (64 z-cols). ring slot tt holds h at time tt. Writes: relaxed agent 8B
// write-through. Reads: plain cached uint4 (fresh lines). Barrier: flag[dir*32+
// cblk] = steps completed (monotonic); wave0 polls all 32 flags in one load.
__global__ __launch_bounds__(256, 1) void scan_ring_kernel(
    const __half* __restrict__ xzf, const __half* __restrict__ xzb,
    const float* __restrict__ Uf, const float* __restrict__ Ub,
    const int* __restrict__ text,
    __half* ring,
    int* flags, int* abortf,
    float* __restrict__ hT_out) {
  __shared__ __align__(16) _Float16 s_h[64 * 512];   // 64KB h tile, XOR swizzle
  __shared__ __align__(16) float    s_z[64 * 68];    // 17.4KB z
  __shared__ int s_brk;

  const int t    = threadIdx.x;
  const int bi   = blockIdx.x;
  const int dir  = bi >> 5;
  const int cblk = bi & 31;
  const int hc0  = cblk * 16;
  const __half* xz = dir ? xzb : xzf;
  const float* U = dir ? Ub : Uf;
  int* myflags = flags + dir * 32;

  const int w    = t >> 6;          // wave = m-tile (rows w*16..w*16+16)
  const int lane = t & 63;
  const int l16  = lane & 15;
  const int quad = lane >> 4;

  // persistent U B-frags: ufrag[kt][nt][jj] = U[kt*32+quad*8+jj][nt*512+hc0+l16]
  half8_t ufrag[16][4];
#pragma unroll
  for (int nt = 0; nt < 4; nt++) {
    int col = nt * NH + hc0 + l16;
#pragma unroll
    for (int kt = 0; kt < 16; kt++)
#pragma unroll
      for (int jj = 0; jj < 8; jj++)
        ufrag[kt][nt][jj] = (_Float16)U[(size_t)(kt * 32 + quad * 8 + jj) * N4H + col];
  }

  // LSTM state: thread owns row = t>>2, cols jb..jb+3 (jb = (t&3)*4)
  const int srow = t >> 2;
  const int jb   = (t & 3) * 4;
  const int row0 = w * 16 + quad * 4;
  float c_st[4] = {0.f, 0.f, 0.f, 0.f}, h_st[4] = {0.f, 0.f, 0.f, 0.f};

  // xz prefetch registers (16 scalars per thread, step-s values)
  __half xzr[16];
  {
    int tt0 = dir ? (NS - 1) : 0;
#pragma unroll
    for (int nt = 0; nt < 4; nt++)
#pragma unroll
      for (int r4 = 0; r4 < 4; r4++)
        xzr[nt * 4 + r4] = xz[((size_t)(row0 + r4) * NS + tt0) * N4H + nt * NH + hc0 + l16];
  }

  for (int s = 0; s < NS; s++) {
    const int tt = dir ? (NS - 1 - s) : s;
    f32x4_t acc[4] = {{0.f,0.f,0.f,0.f},{0.f,0.f,0.f,0.f},{0.f,0.f,0.f,0.f},{0.f,0.f,0.f,0.f}};

    if (s > 0) {
      const int ttp = dir ? (tt + 1) : (tt - 1);   // slot holding h(s-1)
      // stage h(s-1): 64 rows x 512 fp16 via plain cached uint4; chunk ch at ch^row
#pragma unroll
      for (int i = 0; i < 16; i++) {
        int e   = i * 256 + t;        // 16B chunk id 0..4095
        int row = e >> 6;
        int ch  = e & 63;
        *(uint4*)(s_h + row * 512 + (ch ^ row) * 8) =
            *(const uint4*)(ring + ((size_t)row * NS + ttp) * 1024 + dir * NH + ch * 8);
      }
      __syncthreads();
      const int r = w * 16 + l16;
#pragma unroll
      for (int kt = 0; kt < 16; kt++) {
        int chunk = (kt * 4 + quad) ^ r;
        half8_t af = *(const half8_t*)(s_h + r * 512 + chunk * 8);
#pragma unroll
        for (int nt = 0; nt < 4; nt++)
          acc[nt] = __builtin_amdgcn_mfma_f32_16x16x32_f16(af, ufrag[kt][nt], acc[nt], 0, 0, 0);
      }
    }

    // dump z = acc + xz(prefetched) into s_z[64][68]; gate g == n-tile nt
#pragma unroll
    for (int nt = 0; nt < 4; nt++)
#pragma unroll
      for (int r4 = 0; r4 < 4; r4++)
        s_z[(row0 + r4) * 68 + nt * 16 + l16] = acc[nt][r4] + __half2float(xzr[nt * 4 + r4]);
    __syncthreads();

    // gate update: 4 states per thread (row srow, cols jb..jb+3)
    {
      bool m = text[srow * NS + tt] != 0;
      float4 zi = *(const float4*)&s_z[srow * 68 + 0  + jb];
      float4 zf = *(const float4*)&s_z[srow * 68 + 16 + jb];
      float4 zg = *(const float4*)&s_z[srow * 68 + 32 + jb];
      float4 zo = *(const float4*)&s_z[srow * 68 + 48 + jb];
      float ziv[4] = {zi.x, zi.y, zi.z, zi.w};
      float zfv[4] = {zf.x, zf.y, zf.z, zf.w};
      float zgv[4] = {zg.x, zg.y, zg.z, zg.w};
      float zov[4] = {zo.x, zo.y, zo.z, zo.w};
      union { __half h[4]; unsigned long long u; } pk;
#pragma unroll
      for (int u = 0; u < 4; u++) {
        float ig = 1.f / (1.f + expf(-ziv[u]));
        float fg = 1.f / (1.f + expf(-zfv[u]));
        float gv = tanhf(zgv[u]);
        float og = 1.f / (1.f + expf(-zov[u]));
        float cn = fg * c_st[u] + ig * gv;
        float hn = og * tanhf(cn);
        if (m) { c_st[u] = cn; h_st[u] = hn; }
        pk.h[u] = __float2half(h_st[u]);
      }
      // write-through (LLC) 8B store into ring slot tt
      size_t haddr = ((size_t)srow * NS + tt) * 1024 + dir * NH + hc0 + jb;
      __hip_atomic_store((unsigned long long*)ring + (haddr >> 2), pk.u,
                         __ATOMIC_RELAXED, __HIP_MEMORY_SCOPE_AGENT);
      if (hT_out && s == NS - 1) {
#pragma unroll
        for (int u = 0; u < 4; u++)
          hT_out[(size_t)srow * 1024 + dir * NH + hc0 + jb + u] = h_st[u];
      }
    }

    if (s < NS - 1) {
      // prefetch xz(s+1) BEFORE the drain: latency hides under store-ack + poll
      {
        int ttn = dir ? (tt - 1) : (tt + 1);
#pragma unroll
        for (int nt = 0; nt < 4; nt++)
#pragma unroll
          for (int r4 = 0; r4 < 4; r4++)
            xzr[nt * 4 + r4] = xz[((size_t)(row0 + r4) * NS + ttn) * N4H + nt * NH + hc0 + l16];
      }
      __syncthreads();      // drains vmcnt(0): ring stores LLC-visible; s_z reads done
      if (t < 64) {
        if (t == 0)
          __hip_atomic_store(myflags + cblk, s + 1, __ATOMIC_RELAXED, __HIP_MEMORY_SCOPE_AGENT);
        int it = 0;
        while (true) {
          int f = __hip_atomic_load(myflags + (lane & 31),
                                    __ATOMIC_RELAXED, __HIP_MEMORY_SCOPE_AGENT);
          if (__all(f >= s + 1)) break;
          __builtin_amdgcn_s_sleep(2);
          if (((++it) & 1023) == 0) {
            if (it > 200000)
              __hip_atomic_store(abortf, 1, __ATOMIC_RELAXED, __HIP_MEMORY_SCOPE_AGENT);
            if (__hip_atomic_load(abortf, __ATOMIC_RELAXED, __HIP_MEMORY_SCOPE_AGENT)) break;
          }
        }
        if (t == 0)
          s_brk = __hip_atomic_load(abortf, __ATOMIC_RELAXED, __HIP_MEMORY_SCOPE_AGENT);
      }
      __syncthreads();      // barrier passed; also protects s_h rewrite next iter
      if (s_brk) return;    // fast-fail instead of hang
    }
  }
}

// ---------- fp32 SMEM GEMM (head only) ----------
template <int ACT>
__global__ __launch_bounds__(256) void gemm_kernel(
    const float* __restrict__ A, const float* __restrict__ W,
    const float* __restrict__ bias, float* __restrict__ C,
    int M, int N, int K) {
  __shared__ __align__(16) float As[8][128];
  __shared__ __align__(16) float Bs[8][128];
  const int t  = threadIdx.x;
  const int bn = blockIdx.x * 128;
  const int bm = blockIdx.y * 128;
  const int tx = t & 15, ty = t >> 4;
  const int lm  = t >> 1;
  const int lk4 = (t & 1) * 4;
  const int lbk = t >> 5;
  const int lbn = (t & 31) * 4;
  float acc[8][8];
#pragma unroll
  for (int i = 0; i < 8; i++)
#pragma unroll
    for (int j = 0; j < 8; j++) acc[i][j] = 0.f;

  for (int k0 = 0; k0 < K; k0 += 8) {
#pragma unroll
    for (int i = 0; i < 4; i++) {
      int k = k0 + lk4 + i;
      int m = bm + lm;
      float v = 0.f;
      if (k < K && m < M) v = A[(size_t)m * K + k];
      As[lk4 + i][lm] = v;
    }
    {
      int k = k0 + lbk;
      float4 v = make_float4(0.f, 0.f, 0.f, 0.f);
      if (k < K) v = *(const float4*)(W + (size_t)k * N + bn + lbn);
      *(float4*)(&Bs[lbk][lbn]) = v;
    }
    __syncthreads();
#pragma unroll
    for (int kk = 0; kk < 8; kk++) {
      float a[8], b[8];
      *(float4*)(a)     = *(const float4*)(&As[kk][ty * 8]);
      *(float4*)(a + 4) = *(const float4*)(&As[kk][ty * 8 + 4]);
      *(float4*)(b)     = *(const float4*)(&Bs[kk][tx * 8]);
      *(float4*)(b + 4) = *(const float4*)(&Bs[kk][tx * 8 + 4]);
#pragma unroll
      for (int i = 0; i < 8; i++)
#pragma unroll
        for (int j = 0; j < 8; j++) acc[i][j] += a[i] * b[j];
    }
    __syncthreads();
  }
  float4 bv0 = *(const float4*)(bias + bn + tx * 8);
  float4 bv1 = *(const float4*)(bias + bn + tx * 8 + 4);
#pragma unroll
  for (int i = 0; i < 8; i++) {
    int m = bm + ty * 8 + i;
    if (m >= M) continue;
    float4 o0, o1;
    o0.x = acc[i][0] + bv0.x; o0.y = acc[i][1] + bv0.y;
    o0.z = acc[i][2] + bv0.z; o0.w = acc[i][3] + bv0.w;
    o1.x = acc[i][4] + bv1.x; o1.y = acc[i][5] + bv1.y;
    o1.z = acc[i][6] + bv1.z; o1.w = acc[i][7] + bv1.w;
    if (ACT == 1) {
      o0.x = o0.x >= 0.f ? o0.x : 0.2f * o0.x;  o0.y = o0.y >= 0.f ? o0.y : 0.2f * o0.y;
      o0.z = o0.z >= 0.f ? o0.z : 0.2f * o0.z;  o0.w = o0.w >= 0.f ? o0.w : 0.2f * o0.w;
      o1.x = o1.x >= 0.f ? o1.x : 0.2f * o1.x;  o1.y = o1.y >= 0.f ? o1.y : 0.2f * o1.y;
      o1.z = o1.z >= 0.f ? o1.z : 0.2f * o1.z;  o1.w = o1.w >= 0.f ? o1.w : 0.2f * o1.w;
    }
    *(float4*)(C + (size_t)m * N + bn + tx * 8)     = o0;
    *(float4*)(C + (size_t)m * N + bn + tx * 8 + 4) = o1;
  }
}

__global__ void final_kernel(const float* __restrict__ a1, const float* __restrict__ w,
                             const float* __restrict__ bias, float* __restrict__ out) {
  const int b = blockIdx.x, t = threadIdx.x;
  float v = a1[b * 256 + t] * w[t];
#pragma unroll
  for (int off = 32; off > 0; off >>= 1) v += __shfl_down(v, off, 64);
  __shared__ float red[4];
  if ((t & 63) == 0) red[t >> 6] = v;
  __syncthreads();
  if (t == 0) out[b] = (red[0] + red[1]) + (red[2] + red[3]) + bias[0];
}

extern "C" void kernel_launch(void* const* d_in, const int* in_sizes, int n_in,
                              void* d_out, int out_size, void* d_ws, size_t ws_size,
                              hipStream_t stream) {
  const int*   text = (const int*)  d_in[0];
  const float* emb  = (const float*)d_in[1];
  const float* W0f  = (const float*)d_in[2];
  const float* U0f  = (const float*)d_in[3];
  const float* b0f  = (const float*)d_in[4];
  const float* W0b  = (const float*)d_in[5];
  const float* U0b  = (const float*)d_in[6];
  const float* b0b  = (const float*)d_in[7];
  const float* W1f  = (const float*)d_in[8];
  const float* U1f  = (const float*)d_in[9];
  const float* b1f  = (const float*)d_in[10];
  const float* W1b  = (const float*)d_in[11];
  const float* U1b  = (const float*)d_in[12];
  const float* b1b  = (const float*)d_in[13];
  const float* d0w  = (const float*)d_in[14];
  const float* d0b  = (const float*)d_in[15];
  const float* d1w  = (const float*)d_in[16];
  const float* d1b  = (const float*)d_in[17];
  const float* d2w  = (const float*)d_in[18];
  const float* d2b  = (const float*)d_in[19];
  float* out = (float*)d_out;

  // workspace carve: identical to proven footprint (168,955,904 B)
  char* p = (char*)d_ws;
  __half* xzA = (__half*)p;  p += (size_t)NB * NS * N4H * 2;
  __half* xzB = (__half*)p;  p += (size_t)NB * NS * N4H * 2;
  char* region1 = p;         p += (size_t)NB * NS * 1024 * 2;
  _Float16* x_emb = (_Float16*)region1;   // dead before hs0 written
  __half*   hs0   = (__half*)region1;     // layer-0 ring == hs output; layer-1 ring reuses
  __half* hp0  = (__half*)p;  p += 64 * 1024 * 2;   // unused (carve kept identical)
  __half* hp1  = (__half*)p;  p += 64 * 1024 * 2;   // unused
  int*    cnt  = (int*)p;     p += 64 * 1024 * 4;   // barrier flags + abort
  float*  feat = (float*)p;   p += 64 * 1024 * 4;
  float*  a0   = (float*)p;   p += 64 * 512 * 4;
  float*  a1   = (float*)p;   p += 64 * 256 * 4;
  (void)hp0; (void)hp1;
  int* flags0 = cnt;          // layer0: [dir*32 + cblk], monotonic step count
  int* flags1 = cnt + 64;     // layer1
  int* abortf = cnt + 128;

  hipMemsetAsync(cnt, 0, 129 * sizeof(int), stream);
  hipLaunchKernelGGL(embed_f16_kernel, dim3(4096), dim3(256), 0, stream, text, emb, x_emb);

  dim3 gmf(16, 128);
  hipLaunchKernelGGL(gemm_mfma_kernel, gmf, dim3(256), 0, stream, x_emb, W0f, b0f, xzA, 16384, N4H, NDP, ND);
  hipLaunchKernelGGL(gemm_mfma_kernel, gmf, dim3(256), 0, stream, x_emb, W0b, b0b, xzB, 16384, N4H, NDP, ND);

  hipLaunchKernelGGL(scan_ring_kernel, dim3(64), dim3(256), 0, stream,
                     xzA, xzB, U0f, U0b, text, hs0, flags0, abortf, (float*)nullptr);

  hipLaunchKernelGGL(gemm_mfma_kernel, gmf, dim3(256), 0, stream, (const _Float16*)hs0, W1f, b1f, xzA, 16384, N4H, 1024, 1024);
  hipLaunchKernelGGL(gemm_mfma_kernel, gmf, dim3(256), 0, stream, (const _Float16*)hs0, W1b, b1b, xzB, 16384, N4H, 1024, 1024);

  // layer-1 ring reuses region1 (hs0 dead after the two GEMMs above)
  hipLaunchKernelGGL(scan_ring_kernel, dim3(64), dim3(256), 0, stream,
                     xzA, xzB, U1f, U1b, text, hs0, flags1, abortf, feat);

  gemm_kernel<1><<<dim3(4, 1), dim3(256), 0, stream>>>(feat, d0w, d0b, a0, 64, 512, 1024);
  gemm_kernel<1><<<dim3(2, 1), dim3(256), 0, stream>>>(a0, d1w, d1b, a1, 64, 256, 512);
  hipLaunchKernelGGL(final_kernel, dim3(64), dim3(256), 0, stream, a1, d2w, d2b, out);
}